// Round 1
// baseline (660.723 us; speedup 1.0000x reference)
//
#include <hip/hip_runtime.h>

// Modulated deformable conv2d (DCNv2), fp32, fused single kernel.
// N=8, C=128, H=W=96, Co=128, K=3, stride=1, pad=1, dil=1, DG=1.

#define NI 8
#define CI 128
#define HI 96
#define WI 96
#define CO 128
#define K2 9
#define HO 96
#define WO 96
#define P_TOT (HO * WO)        // 9216 output pixels per image
#define TP 64                  // pixels per block tile
#define NTILE (P_TOT / TP)     // 144
#define CC 8                   // input channels per chunk
#define NCHUNK (CI / CC)       // 16
#define CKC (CC * K2)          // 72 (c,k) pairs per chunk
#define WPAD 132               // padded o-row for s_w (132%4==0 -> aligned float4)

__global__ __launch_bounds__(256, 2)
void dcn_fused_kernel(const float* __restrict__ x,
                      const float* __restrict__ offset,
                      const float* __restrict__ mask,
                      const float* __restrict__ weight,
                      const float* __restrict__ bias,
                      float* __restrict__ out)
{
    // meta: per (tap k, pixel i): 4 corner indices (int bits) + 4 weights (mask folded)
    __shared__ float s_meta[K2 * TP * 8];   // 18432 B
    __shared__ float s_v[CKC * TP];         // 18432 B   v[ck][i]
    __shared__ float s_w[CKC * WPAD];       // 38016 B   w[ck][o] (padded)

    const int tid = threadIdx.x;
    const int bid = blockIdx.x;
    const int n  = bid / NTILE;
    const int p0 = (bid % NTILE) * TP;

    // ---------------- Phase A: bilinear meta (once per block) ----------------
    for (int it = 0; it < 3; ++it) {
        int item = it * 256 + tid;          // k*TP + i, item < 576
        if (item < K2 * TP) {
            int k = item / TP;
            int i = item % TP;
            int p  = p0 + i;
            int ph = p / WO;
            int pw = p % WO;
            float offy = offset[((size_t)n * (2 * K2) + 2 * k    ) * P_TOT + p];
            float offx = offset[((size_t)n * (2 * K2) + 2 * k + 1) * P_TOT + p];
            float m    = mask  [((size_t)n * K2 + k) * P_TOT + p];
            int ky = k / 3, kx = k % 3;
            float py = (float)(ph - 1 + ky) + offy;   // stride=1, pad=1, dil=1
            float px = (float)(pw - 1 + kx) + offx;
            float y0f = floorf(py), x0f = floorf(px);
            float wy = py - y0f, wx = px - x0f;
            int y0 = (int)y0f, x0 = (int)x0f;
            int y1 = y0 + 1,  x1 = x0 + 1;
            bool vy0 = (y0 >= 0) && (y0 < HI);
            bool vy1 = (y1 >= 0) && (y1 < HI);
            bool vx0 = (x0 >= 0) && (x0 < WI);
            bool vx1 = (x1 >= 0) && (x1 < WI);
            int i00 = (vy0 && vx0) ? (y0 * WI + x0) : 0;
            int i01 = (vy0 && vx1) ? (y0 * WI + x1) : 0;
            int i10 = (vy1 && vx0) ? (y1 * WI + x0) : 0;
            int i11 = (vy1 && vx1) ? (y1 * WI + x1) : 0;
            float w00 = (vy0 && vx0) ? (1.f - wy) * (1.f - wx) * m : 0.f;
            float w01 = (vy0 && vx1) ? (1.f - wy) * wx          * m : 0.f;
            float w10 = (vy1 && vx0) ? wy * (1.f - wx)          * m : 0.f;
            float w11 = (vy1 && vx1) ? wy * wx                  * m : 0.f;
            float4* mp = (float4*)&s_meta[item * 8];
            mp[0] = make_float4(__int_as_float(i00), __int_as_float(i01),
                                __int_as_float(i10), __int_as_float(i11));
            mp[1] = make_float4(w00, w01, w10, w11);
        }
    }
    __syncthreads();

    float acc[4][8];
    #pragma unroll
    for (int a = 0; a < 4; ++a)
        #pragma unroll
        for (int b = 0; b < 8; ++b) acc[a][b] = 0.f;

    const int og = tid & 31;   // o-group: owns o = og*4 .. og*4+3
    const int pg = tid >> 5;   // p-group: owns p = pg*8 .. pg*8+7

    for (int ch = 0; ch < NCHUNK; ++ch) {
        const int c0 = ch * CC;

        // ---- gather v[cc][k][i] for this channel chunk ----
        #pragma unroll 2
        for (int it = 0; it < 18; ++it) {
            int item = it * 256 + tid;          // < 4608 = CC*K2*TP
            int cc  = item / (K2 * TP);
            int rem = item % (K2 * TP);         // k*TP + i
            const float4* mp = (const float4*)&s_meta[rem * 8];
            float4 mi = mp[0];
            float4 mw = mp[1];
            int i00 = __float_as_int(mi.x);
            int i01 = __float_as_int(mi.y);
            int i10 = __float_as_int(mi.z);
            int i11 = __float_as_int(mi.w);
            const float* xb = x + ((size_t)n * CI + c0 + cc) * (HI * WI);
            float v = mw.x * xb[i00] + mw.y * xb[i01]
                    + mw.z * xb[i10] + mw.w * xb[i11];
            s_v[item] = v;                      // item == (cc*K2+k)*TP + i
        }

        // ---- stage transposed weight slab w[ck][o] ----
        #pragma unroll 4
        for (int it = 0; it < 36; ++it) {
            int item = it * 256 + tid;          // < 9216 = CO*CKC
            int o = item / CKC;
            int j = item % CKC;                 // cc*K2 + k
            s_w[j * WPAD + o] = weight[(size_t)o * (CI * K2) + c0 * K2 + j];
        }
        __syncthreads();

        // ---- register-tiled FMA: out[o, p] += w[ck][o] * v[ck][p] ----
        const float4* v4 = (const float4*)s_v;
        const float4* w4 = (const float4*)s_w;
        #pragma unroll 4
        for (int ck = 0; ck < CKC; ++ck) {
            float4 wv = w4[ck * (WPAD / 4) + og];
            float4 va = v4[ck * (TP / 4) + pg * 2];
            float4 vb = v4[ck * (TP / 4) + pg * 2 + 1];
            float wvv[4] = {wv.x, wv.y, wv.z, wv.w};
            float vvv[8] = {va.x, va.y, va.z, va.w, vb.x, vb.y, vb.z, vb.w};
            #pragma unroll
            for (int oo = 0; oo < 4; ++oo)
                #pragma unroll
                for (int pp = 0; pp < 8; ++pp)
                    acc[oo][pp] += wvv[oo] * vvv[pp];
        }
        __syncthreads();
    }

    // ---------------- epilogue: bias + store ----------------
    #pragma unroll
    for (int oo = 0; oo < 4; ++oo) {
        int o = og * 4 + oo;
        float b = bias[o];
        float* rowp = out + ((size_t)n * CO + o) * P_TOT + p0 + pg * 8;
        float4 r0 = make_float4(acc[oo][0] + b, acc[oo][1] + b,
                                acc[oo][2] + b, acc[oo][3] + b);
        float4 r1 = make_float4(acc[oo][4] + b, acc[oo][5] + b,
                                acc[oo][6] + b, acc[oo][7] + b);
        ((float4*)rowp)[0] = r0;
        ((float4*)rowp)[1] = r1;
    }
}

extern "C" void kernel_launch(void* const* d_in, const int* in_sizes, int n_in,
                              void* d_out, int out_size, void* d_ws, size_t ws_size,
                              hipStream_t stream) {
    const float* x      = (const float*)d_in[0];
    const float* offset = (const float*)d_in[1];
    const float* mask   = (const float*)d_in[2];
    const float* weight = (const float*)d_in[3];
    const float* bias   = (const float*)d_in[4];
    float* out = (float*)d_out;

    dim3 grid(NI * NTILE);
    dim3 block(256);
    dcn_fused_kernel<<<grid, block, 0, stream>>>(x, offset, mask, weight, bias, out);
}

// Round 2
// 384.005 us; speedup vs baseline: 1.7206x; 1.7206x over previous
//
#include <hip/hip_runtime.h>

// Modulated deformable conv2d (DCNv2), fused, bf16-MFMA GEMM.
// N=8, C=128, H=W=96, Co=128, K=3, stride=1, pad=1, dil=1, DG=1.
// Structure: per block = (image n, 64-pixel tile). K-order = (cb: 4 blocks of
// 32 channels) x (k: 9 taps); each chunk is one MFMA K=32 slab.
// Gather (bilinear+mask, fp32 math) -> LDS bf16 v[p][c]; weights pre-cast to
// bf16 wt[k][o][c] in d_ws once per launch; MFMA f32_16x16x32_bf16.

#define NI 8
#define CI 128
#define HW_ (96 * 96)          // 9216 pixels per plane
#define HI 96
#define WI 96
#define CO 128
#define K2 9
#define P_TOT 9216
#define TP 64                  // pixels per block tile
#define NTILE (P_TOT / TP)     // 144
#define CPAD 40                // padded c-extent of LDS rows (breaks conflicts)
#define WT_ELEMS (K2 * CO * CI)   // 147456 bf16 elements in d_ws

typedef short short8 __attribute__((ext_vector_type(8)));
typedef float f32x4 __attribute__((ext_vector_type(4)));

__device__ __forceinline__ ushort bf16_rne(float x) {
    unsigned u = __float_as_uint(x);
    u = (u + 0x7FFF + ((u >> 16) & 1)) >> 16;
    return (ushort)u;
}
__device__ __forceinline__ unsigned pack_bf2(float a, float b) {
    return (unsigned)bf16_rne(a) | ((unsigned)bf16_rne(b) << 16);
}

// ---- one-time (per launch) weight transform: wt[k][o][c] bf16 ----
__global__ void wt_transform_kernel(const float* __restrict__ w,
                                    ushort* __restrict__ wt) {
    int idx = blockIdx.x * 256 + threadIdx.x;       // < 147456
    int k   = idx >> 14;                            // /16384  (0..8)
    int rem = idx & 16383;
    int o = rem >> 7, c = rem & 127;
    wt[idx] = bf16_rne(w[(size_t)o * (CI * K2) + c * K2 + k]);
}

template <int USE_WT>
__global__ __launch_bounds__(256, 3)
void dcn_mfma_kernel(const float* __restrict__ x,
                     const float* __restrict__ offset,
                     const float* __restrict__ mask,
                     const float* __restrict__ weight,
                     const float* __restrict__ bias,
                     const ushort* __restrict__ wt,
                     float* __restrict__ out)
{
    __shared__ uint2  s_midx[K2 * TP];     // 4 packed u16 corner indices
    __shared__ float4 s_mw[K2 * TP];       // 4 bilinear*mask weights (fp32)
    __shared__ ushort s_v[TP * CPAD];      // v[p][c'] bf16, c' padded to 40
    __shared__ ushort s_w[CO * CPAD];      // w[o][c'] bf16

    const int tid  = threadIdx.x;
    const int bid  = blockIdx.x;
    const int n    = bid & 7;              // XCD swizzle: image n pinned per XCD
    const int tile = bid >> 3;
    const int p0   = tile * TP;

    // ---------------- meta phase: bilinear corners + weights ----------------
    for (int it = 0; it < 3; ++it) {
        int item = it * 256 + tid;                 // k*TP + i, < 576
        if (item < K2 * TP) {
            int k = item / TP;
            int i = item % TP;
            int p  = p0 + i;
            int ph = p / WI;
            int pw = p % WI;
            float offy = offset[((size_t)n * (2 * K2) + 2 * k    ) * P_TOT + p];
            float offx = offset[((size_t)n * (2 * K2) + 2 * k + 1) * P_TOT + p];
            float m    = mask  [((size_t)n * K2 + k) * P_TOT + p];
            int ky = k / 3, kx = k % 3;
            float py = (float)(ph - 1 + ky) + offy;
            float px = (float)(pw - 1 + kx) + offx;
            float y0f = floorf(py), x0f = floorf(px);
            float wy = py - y0f, wx = px - x0f;
            int y0 = (int)y0f, x0 = (int)x0f;
            int y1 = y0 + 1,  x1 = x0 + 1;
            bool vy0 = (y0 >= 0) && (y0 < HI);
            bool vy1 = (y1 >= 0) && (y1 < HI);
            bool vx0 = (x0 >= 0) && (x0 < WI);
            bool vx1 = (x1 >= 0) && (x1 < WI);
            unsigned i00 = (vy0 && vx0) ? (unsigned)(y0 * WI + x0) : 0u;
            unsigned i01 = (vy0 && vx1) ? (unsigned)(y0 * WI + x1) : 0u;
            unsigned i10 = (vy1 && vx0) ? (unsigned)(y1 * WI + x0) : 0u;
            unsigned i11 = (vy1 && vx1) ? (unsigned)(y1 * WI + x1) : 0u;
            float w00 = (vy0 && vx0) ? (1.f - wy) * (1.f - wx) * m : 0.f;
            float w01 = (vy0 && vx1) ? (1.f - wy) * wx          * m : 0.f;
            float w10 = (vy1 && vx0) ? wy * (1.f - wx)          * m : 0.f;
            float w11 = (vy1 && vx1) ? wy * wx                  * m : 0.f;
            s_midx[item] = make_uint2(i00 | (i01 << 16), i10 | (i11 << 16));
            s_mw[item]   = make_float4(w00, w01, w10, w11);
        }
    }
    __syncthreads();

    const int wave = tid >> 6;
    const int lane = tid & 63;
    const int l15  = lane & 15;
    const int quad = lane >> 4;
    // MFMA wave tiling: 2x2 waves, each 64 o x 32 p
    const int o_base = (wave >> 1) * 64;
    const int p_base = (wave & 1) * 32;
    // gather assignment: thread -> (p = tid&63, channel group = wave)
    const int gp = tid & 63;
    const int cg = wave;

    f32x4 acc[4][2];
    #pragma unroll
    for (int a = 0; a < 4; ++a)
        #pragma unroll
        for (int b = 0; b < 2; ++b)
            acc[a][b] = (f32x4){0.f, 0.f, 0.f, 0.f};

    for (int cb = 0; cb < 4; ++cb) {           // 32-channel blocks (outer: L1 reuse)
        for (int k = 0; k < K2; ++k) {         // taps (inner: reuse x lines)
            // ---- gather: v[p][c'] bf16, 8 channels per thread ----
            {
                uint2  mi = s_midx[k * TP + gp];
                float4 mw = s_mw[k * TP + gp];
                int i00 = mi.x & 0xFFFF, i01 = mi.x >> 16;
                int i10 = mi.y & 0xFFFF, i11 = mi.y >> 16;
                const float* xb = x + ((size_t)(n * CI + cb * 32 + cg * 8)) * HW_;
                float v[8];
                #pragma unroll
                for (int j = 0; j < 8; ++j) {
                    const float* xp = xb + (size_t)j * HW_;
                    v[j] = mw.x * xp[i00] + mw.y * xp[i01]
                         + mw.z * xp[i10] + mw.w * xp[i11];
                }
                uint4 pk;
                pk.x = pack_bf2(v[0], v[1]);
                pk.y = pack_bf2(v[2], v[3]);
                pk.z = pack_bf2(v[4], v[5]);
                pk.w = pack_bf2(v[6], v[7]);
                *(uint4*)&s_v[gp * CPAD + cg * 8] = pk;
            }
            // ---- stage weights: w[o][c'] bf16 (32 c' for this tap) ----
            {
                int o = tid >> 1, half = tid & 1;
                if (USE_WT) {
                    const uint4* src = (const uint4*)(wt + (size_t)k * (CO * CI)
                                                     + o * CI + cb * 32 + half * 16);
                    uint4 a = src[0];
                    uint4 b = src[1];
                    *(uint4*)&s_w[o * CPAD + half * 16]     = a;
                    *(uint4*)&s_w[o * CPAD + half * 16 + 8] = b;
                } else {
                    const float* wsrc = weight + (size_t)o * (CI * K2)
                                      + (cb * 32 + half * 16) * K2 + k;
                    ushort tmp[16];
                    #pragma unroll
                    for (int i = 0; i < 16; ++i) tmp[i] = bf16_rne(wsrc[i * K2]);
                    *(uint4*)&s_w[o * CPAD + half * 16]     = *(uint4*)&tmp[0];
                    *(uint4*)&s_w[o * CPAD + half * 16 + 8] = *(uint4*)&tmp[8];
                }
            }
            __syncthreads();

            // ---- MFMA: 8x 16x16x32 per wave ----
            short8 afr[4], bfr[2];
            #pragma unroll
            for (int ot = 0; ot < 4; ++ot)
                afr[ot] = *(const short8*)&s_w[(o_base + ot * 16 + l15) * CPAD + quad * 8];
            #pragma unroll
            for (int pt = 0; pt < 2; ++pt)
                bfr[pt] = *(const short8*)&s_v[(p_base + pt * 16 + l15) * CPAD + quad * 8];
            #pragma unroll
            for (int ot = 0; ot < 4; ++ot)
                #pragma unroll
                for (int pt = 0; pt < 2; ++pt)
                    acc[ot][pt] = __builtin_amdgcn_mfma_f32_16x16x32_bf16(
                        afr[ot], bfr[pt], acc[ot][pt], 0, 0, 0);
            __syncthreads();
        }
    }

    // ---------------- epilogue: bias + store ----------------
    #pragma unroll
    for (int ot = 0; ot < 4; ++ot) {
        #pragma unroll
        for (int r = 0; r < 4; ++r) {
            int o = o_base + ot * 16 + quad * 4 + r;
            float b = bias[o];
            #pragma unroll
            for (int pt = 0; pt < 2; ++pt) {
                int p = p0 + p_base + pt * 16 + l15;
                out[((size_t)n * CO + o) * P_TOT + p] = acc[ot][pt][r] + b;
            }
        }
    }
}

extern "C" void kernel_launch(void* const* d_in, const int* in_sizes, int n_in,
                              void* d_out, int out_size, void* d_ws, size_t ws_size,
                              hipStream_t stream) {
    const float* x      = (const float*)d_in[0];
    const float* offset = (const float*)d_in[1];
    const float* mask   = (const float*)d_in[2];
    const float* weight = (const float*)d_in[3];
    const float* bias   = (const float*)d_in[4];
    float* out = (float*)d_out;
    ushort* wt = (ushort*)d_ws;

    dim3 block(256);
    if (ws_size >= (size_t)WT_ELEMS * sizeof(ushort)) {
        wt_transform_kernel<<<dim3(WT_ELEMS / 256), block, 0, stream>>>(weight, wt);
        dcn_mfma_kernel<1><<<dim3(NI * NTILE), block, 0, stream>>>(
            x, offset, mask, weight, bias, wt, out);
    } else {
        dcn_mfma_kernel<0><<<dim3(NI * NTILE), block, 0, stream>>>(
            x, offset, mask, weight, bias, wt, out);
    }
}

// Round 3
// 225.797 us; speedup vs baseline: 2.9262x; 1.7007x over previous
//
#include <hip/hip_runtime.h>

// DCNv2 fused, v3: x transposed to [n][hw][c] bf16 once per launch ->
// bilinear corners are contiguous 256B channel rows -> B-fragments gathered
// straight into registers (no LDS v, no scatter). Weights double-buffered in
// LDS, 1 sync/chunk. MFMA f32_16x16x32_bf16; wave = 16p x 128o.

#define NI 8
#define CI 128
#define HI 96
#define WI 96
#define CO 128
#define K2 9
#define P_TOT 9216
#define TP 64
#define NTILE 144                                   // P_TOT/TP
#define CPAD 40
#define XT_ELEMS ((size_t)NI * P_TOT * CI)          // 9,437,184 bf16
#define WT_ELEMS ((size_t)K2 * CO * CI)             // 147,456 bf16
#define WS_NEED ((XT_ELEMS + WT_ELEMS) * 2)

typedef short short8 __attribute__((ext_vector_type(8)));
typedef float f32x4 __attribute__((ext_vector_type(4)));

static __device__ __forceinline__ ushort bf16_rne(float x) {
    unsigned u = __float_as_uint(x);
    u = (u + 0x7FFF + ((u >> 16) & 1)) >> 16;
    return (ushort)u;
}
static __device__ __forceinline__ unsigned pack_bf2(float a, float b) {
    return (unsigned)bf16_rne(a) | ((unsigned)bf16_rne(b) << 16);
}
static __device__ __forceinline__ float bflo(unsigned u) { return __uint_as_float(u << 16); }
static __device__ __forceinline__ float bfhi(unsigned u) { return __uint_as_float(u & 0xFFFF0000u); }

union U4S8 { uint4 u; short8 s; };

// ---- once per launch: wt[k][o][c] bf16 ----
__global__ __launch_bounds__(256)
void wt_transform_kernel(const float* __restrict__ w, ushort* __restrict__ wt) {
    int idx = blockIdx.x * 256 + threadIdx.x;       // < 147456
    int k   = idx >> 14;
    int rem = idx & 16383;
    int o = rem >> 7, c = rem & 127;
    wt[idx] = bf16_rne(w[(size_t)o * (CI * K2) + c * K2 + k]);
}

// ---- once per launch: xt[n][hw][c] bf16 ----
__global__ __launch_bounds__(256)
void xt_transpose_kernel(const float* __restrict__ x, ushort* __restrict__ xt) {
    __shared__ ushort tile[64][132];
    const int bid = blockIdx.x;                     // n*144 + t
    const int n = bid / NTILE, t = bid % NTILE;
    const int hw0 = t * 64;
    const int tid = threadIdx.x;
    #pragma unroll
    for (int rep = 0; rep < 8; ++rep) {             // read 128c x 64hw (float4)
        int idx = rep * 256 + tid;                  // < 2048
        int c = idx >> 4, iq = idx & 15;
        float4 f = *(const float4*)(x + ((size_t)(n * CI + c)) * P_TOT + hw0 + iq * 4);
        tile[iq * 4 + 0][c] = bf16_rne(f.x);
        tile[iq * 4 + 1][c] = bf16_rne(f.y);
        tile[iq * 4 + 2][c] = bf16_rne(f.z);
        tile[iq * 4 + 3][c] = bf16_rne(f.w);
    }
    __syncthreads();
    #pragma unroll
    for (int rep = 0; rep < 8; ++rep) {             // write 64hw x 128c (uint2)
        int idx = rep * 256 + tid;                  // < 2048
        int i = idx >> 5, cq = idx & 31;
        uint2 v = *(const uint2*)&tile[i][cq * 4];
        *(uint2*)(xt + ((size_t)n * P_TOT + hw0 + i) * CI + cq * 4) = v;
    }
}

__global__ __launch_bounds__(256, 4)
void dcn_mfma2_kernel(const ushort* __restrict__ xt,
                      const ushort* __restrict__ wt,
                      const float* __restrict__ offset,
                      const float* __restrict__ mask,
                      const float* __restrict__ bias,
                      float* __restrict__ out)
{
    __shared__ uint2  s_midx[K2 * TP];      // packed corner row-indices (u16 x4)
    __shared__ float4 s_mw[K2 * TP];        // bilinear*mask weights
    __shared__ ushort s_w[2][CO * CPAD];    // dbuf weight slab w[o][c'] bf16

    const int tid  = threadIdx.x;
    const int bid  = blockIdx.x;
    const int n    = bid & 7;               // XCD swizzle
    const int p0   = (bid >> 3) * TP;

    // ---- meta phase ----
    for (int it = 0; it < 3; ++it) {
        int item = it * 256 + tid;          // k*TP + i, < 576
        if (item < K2 * TP) {
            int k = item / TP;
            int i = item % TP;
            int p  = p0 + i;
            int ph = p / WI;
            int pw = p % WI;
            float offy = offset[((size_t)n * (2 * K2) + 2 * k    ) * P_TOT + p];
            float offx = offset[((size_t)n * (2 * K2) + 2 * k + 1) * P_TOT + p];
            float m    = mask  [((size_t)n * K2 + k) * P_TOT + p];
            int ky = k / 3, kx = k % 3;
            float py = (float)(ph - 1 + ky) + offy;
            float px = (float)(pw - 1 + kx) + offx;
            float y0f = floorf(py), x0f = floorf(px);
            float wy = py - y0f, wx = px - x0f;
            int y0 = (int)y0f, x0 = (int)x0f;
            int y1 = y0 + 1,  x1 = x0 + 1;
            bool vy0 = (y0 >= 0) && (y0 < HI);
            bool vy1 = (y1 >= 0) && (y1 < HI);
            bool vx0 = (x0 >= 0) && (x0 < WI);
            bool vx1 = (x1 >= 0) && (x1 < WI);
            unsigned i00 = (vy0 && vx0) ? (unsigned)(y0 * WI + x0) : 0u;
            unsigned i01 = (vy0 && vx1) ? (unsigned)(y0 * WI + x1) : 0u;
            unsigned i10 = (vy1 && vx0) ? (unsigned)(y1 * WI + x0) : 0u;
            unsigned i11 = (vy1 && vx1) ? (unsigned)(y1 * WI + x1) : 0u;
            float w00 = (vy0 && vx0) ? (1.f - wy) * (1.f - wx) * m : 0.f;
            float w01 = (vy0 && vx1) ? (1.f - wy) * wx          * m : 0.f;
            float w10 = (vy1 && vx0) ? wy * (1.f - wx)          * m : 0.f;
            float w11 = (vy1 && vx1) ? wy * wx                  * m : 0.f;
            s_midx[item] = make_uint2(i00 | (i01 << 16), i10 | (i11 << 16));
            s_mw[item]   = make_float4(w00, w01, w10, w11);
        }
    }

    const int wave = tid >> 6;
    const int lane = tid & 63;
    const int l15  = lane & 15;
    const int quad = lane >> 4;

    f32x4 acc[8];
    #pragma unroll
    for (int a = 0; a < 8; ++a) acc[a] = (f32x4){0.f, 0.f, 0.f, 0.f};

    const int so = tid >> 1, sh = tid & 1;  // weight-stage assignment

    // stage chunk 0 (cb=0,k=0) into buf 0
    {
        const uint4* src = (const uint4*)(wt + (size_t)so * CI + sh * 16);
        uint4 a = src[0], b = src[1];
        __syncthreads();                    // meta visible before main loop
        *(uint4*)&s_w[0][so * CPAD + sh * 16]     = a;
        *(uint4*)&s_w[0][so * CPAD + sh * 16 + 8] = b;
        __syncthreads();
    }

    int ch = 0;
    for (int cb = 0; cb < 4; ++cb) {
        const ushort* xb = xt + (size_t)n * (P_TOT * CI) + cb * 32 + quad * 8;
        for (int k = 0; k < K2; ++k, ++ch) {
            const int buf = ch & 1;
            // stage next chunk into buf^1
            if (ch + 1 < 36) {
                int nch = ch + 1;
                int ncb = nch / 9, nk = nch - ncb * 9;
                const uint4* src = (const uint4*)(wt + (size_t)nk * (CO * CI)
                                                  + so * CI + ncb * 32 + sh * 16);
                uint4 a = src[0], b = src[1];
                *(uint4*)&s_w[buf ^ 1][so * CPAD + sh * 16]     = a;
                *(uint4*)&s_w[buf ^ 1][so * CPAD + sh * 16 + 8] = b;
            }
            // gather B-fragment straight into registers
            uint2  mi = s_midx[k * TP + wave * 16 + l15];
            float4 mw = s_mw[k * TP + wave * 16 + l15];
            uint4 r00 = *(const uint4*)(xb + (size_t)(mi.x & 0xFFFF) * CI);
            uint4 r01 = *(const uint4*)(xb + (size_t)(mi.x >> 16)    * CI);
            uint4 r10 = *(const uint4*)(xb + (size_t)(mi.y & 0xFFFF) * CI);
            uint4 r11 = *(const uint4*)(xb + (size_t)(mi.y >> 16)    * CI);
            float v0 = mw.x * bflo(r00.x) + mw.y * bflo(r01.x) + mw.z * bflo(r10.x) + mw.w * bflo(r11.x);
            float v1 = mw.x * bfhi(r00.x) + mw.y * bfhi(r01.x) + mw.z * bfhi(r10.x) + mw.w * bfhi(r11.x);
            float v2 = mw.x * bflo(r00.y) + mw.y * bflo(r01.y) + mw.z * bflo(r10.y) + mw.w * bflo(r11.y);
            float v3 = mw.x * bfhi(r00.y) + mw.y * bfhi(r01.y) + mw.z * bfhi(r10.y) + mw.w * bfhi(r11.y);
            float v4 = mw.x * bflo(r00.z) + mw.y * bflo(r01.z) + mw.z * bflo(r10.z) + mw.w * bflo(r11.z);
            float v5 = mw.x * bfhi(r00.z) + mw.y * bfhi(r01.z) + mw.z * bfhi(r10.z) + mw.w * bfhi(r11.z);
            float v6 = mw.x * bflo(r00.w) + mw.y * bflo(r01.w) + mw.z * bflo(r10.w) + mw.w * bflo(r11.w);
            float v7 = mw.x * bfhi(r00.w) + mw.y * bfhi(r01.w) + mw.z * bfhi(r10.w) + mw.w * bfhi(r11.w);
            U4S8 cvt;
            cvt.u.x = pack_bf2(v0, v1);
            cvt.u.y = pack_bf2(v2, v3);
            cvt.u.z = pack_bf2(v4, v5);
            cvt.u.w = pack_bf2(v6, v7);
            short8 bfr = cvt.s;
            // 8 MFMAs over the 128-o extent
            #pragma unroll
            for (int ot = 0; ot < 8; ++ot) {
                short8 afr = *(const short8*)&s_w[buf][(ot * 16 + l15) * CPAD + quad * 8];
                acc[ot] = __builtin_amdgcn_mfma_f32_16x16x32_bf16(afr, bfr, acc[ot], 0, 0, 0);
            }
            __syncthreads();
        }
    }

    // ---- epilogue ----
    #pragma unroll
    for (int ot = 0; ot < 8; ++ot) {
        #pragma unroll
        for (int r = 0; r < 4; ++r) {
            int o = ot * 16 + quad * 4 + r;
            int p = p0 + wave * 16 + l15;
            out[((size_t)n * CO + o) * P_TOT + p] = acc[ot][r] + bias[o];
        }
    }
}

// ---------------- fallback (no workspace): round-2 structure ----------------
__global__ __launch_bounds__(256, 3)
void dcn_fallback_kernel(const float* __restrict__ x,
                         const float* __restrict__ offset,
                         const float* __restrict__ mask,
                         const float* __restrict__ weight,
                         const float* __restrict__ bias,
                         float* __restrict__ out)
{
    __shared__ uint2  s_midx[K2 * TP];
    __shared__ float4 s_mw[K2 * TP];
    __shared__ ushort s_v[TP * CPAD];
    __shared__ ushort s_w[CO * CPAD];

    const int tid  = threadIdx.x;
    const int bid  = blockIdx.x;
    const int n    = bid & 7;
    const int p0   = (bid >> 3) * TP;

    for (int it = 0; it < 3; ++it) {
        int item = it * 256 + tid;
        if (item < K2 * TP) {
            int k = item / TP;
            int i = item % TP;
            int p  = p0 + i;
            int ph = p / WI;
            int pw = p % WI;
            float offy = offset[((size_t)n * (2 * K2) + 2 * k    ) * P_TOT + p];
            float offx = offset[((size_t)n * (2 * K2) + 2 * k + 1) * P_TOT + p];
            float m    = mask  [((size_t)n * K2 + k) * P_TOT + p];
            int ky = k / 3, kx = k % 3;
            float py = (float)(ph - 1 + ky) + offy;
            float px = (float)(pw - 1 + kx) + offx;
            float y0f = floorf(py), x0f = floorf(px);
            float wy = py - y0f, wx = px - x0f;
            int y0 = (int)y0f, x0 = (int)x0f;
            int y1 = y0 + 1,  x1 = x0 + 1;
            bool vy0 = (y0 >= 0) && (y0 < HI);
            bool vy1 = (y1 >= 0) && (y1 < HI);
            bool vx0 = (x0 >= 0) && (x0 < WI);
            bool vx1 = (x1 >= 0) && (x1 < WI);
            unsigned i00 = (vy0 && vx0) ? (unsigned)(y0 * WI + x0) : 0u;
            unsigned i01 = (vy0 && vx1) ? (unsigned)(y0 * WI + x1) : 0u;
            unsigned i10 = (vy1 && vx0) ? (unsigned)(y1 * WI + x0) : 0u;
            unsigned i11 = (vy1 && vx1) ? (unsigned)(y1 * WI + x1) : 0u;
            float w00 = (vy0 && vx0) ? (1.f - wy) * (1.f - wx) * m : 0.f;
            float w01 = (vy0 && vx1) ? (1.f - wy) * wx          * m : 0.f;
            float w10 = (vy1 && vx0) ? wy * (1.f - wx)          * m : 0.f;
            float w11 = (vy1 && vx1) ? wy * wx                  * m : 0.f;
            s_midx[item] = make_uint2(i00 | (i01 << 16), i10 | (i11 << 16));
            s_mw[item]   = make_float4(w00, w01, w10, w11);
        }
    }
    __syncthreads();

    const int wave = tid >> 6;
    const int lane = tid & 63;
    const int l15  = lane & 15;
    const int quad = lane >> 4;
    const int o_base = (wave >> 1) * 64;
    const int p_base = (wave & 1) * 32;
    const int gp = tid & 63;
    const int cg = wave;

    f32x4 acc[4][2];
    #pragma unroll
    for (int a = 0; a < 4; ++a)
        #pragma unroll
        for (int b = 0; b < 2; ++b) acc[a][b] = (f32x4){0.f, 0.f, 0.f, 0.f};

    for (int cb = 0; cb < 4; ++cb) {
        for (int k = 0; k < K2; ++k) {
            {
                uint2  mi = s_midx[k * TP + gp];
                float4 mw = s_mw[k * TP + gp];
                int i00 = mi.x & 0xFFFF, i01 = mi.x >> 16;
                int i10 = mi.y & 0xFFFF, i11 = mi.y >> 16;
                const float* xb = x + ((size_t)(n * CI + cb * 32 + cg * 8)) * (HI * WI);
                float v[8];
                #pragma unroll
                for (int j = 0; j < 8; ++j) {
                    const float* xp = xb + (size_t)j * (HI * WI);
                    v[j] = mw.x * xp[i00] + mw.y * xp[i01]
                         + mw.z * xp[i10] + mw.w * xp[i11];
                }
                uint4 pk;
                pk.x = pack_bf2(v[0], v[1]);
                pk.y = pack_bf2(v[2], v[3]);
                pk.z = pack_bf2(v[4], v[5]);
                pk.w = pack_bf2(v[6], v[7]);
                *(uint4*)&s_v[gp * CPAD + cg * 8] = pk;
            }
            {
                int o = tid >> 1, half = tid & 1;
                const float* wsrc = weight + (size_t)o * (CI * K2)
                                  + (cb * 32 + half * 16) * K2 + k;
                ushort tmp[16];
                #pragma unroll
                for (int i = 0; i < 16; ++i) tmp[i] = bf16_rne(wsrc[i * K2]);
                *(uint4*)&s_w[o * CPAD + half * 16]     = *(uint4*)&tmp[0];
                *(uint4*)&s_w[o * CPAD + half * 16 + 8] = *(uint4*)&tmp[8];
            }
            __syncthreads();
            short8 afr[4], bfr[2];
            #pragma unroll
            for (int ot = 0; ot < 4; ++ot)
                afr[ot] = *(const short8*)&s_w[(o_base + ot * 16 + l15) * CPAD + quad * 8];
            #pragma unroll
            for (int pt = 0; pt < 2; ++pt)
                bfr[pt] = *(const short8*)&s_v[(p_base + pt * 16 + l15) * CPAD + quad * 8];
            #pragma unroll
            for (int ot = 0; ot < 4; ++ot)
                #pragma unroll
                for (int pt = 0; pt < 2; ++pt)
                    acc[ot][pt] = __builtin_amdgcn_mfma_f32_16x16x32_bf16(
                        afr[ot], bfr[pt], acc[ot][pt], 0, 0, 0);
            __syncthreads();
        }
    }

    #pragma unroll
    for (int ot = 0; ot < 4; ++ot)
        #pragma unroll
        for (int r = 0; r < 4; ++r) {
            int o = o_base + ot * 16 + quad * 4 + r;
            float b = bias[o];
            #pragma unroll
            for (int pt = 0; pt < 2; ++pt) {
                int p = p0 + p_base + pt * 16 + l15;
                out[((size_t)n * CO + o) * P_TOT + p] = acc[ot][pt][r] + b;
            }
        }
}

extern "C" void kernel_launch(void* const* d_in, const int* in_sizes, int n_in,
                              void* d_out, int out_size, void* d_ws, size_t ws_size,
                              hipStream_t stream) {
    const float* x      = (const float*)d_in[0];
    const float* offset = (const float*)d_in[1];
    const float* mask   = (const float*)d_in[2];
    const float* weight = (const float*)d_in[3];
    const float* bias   = (const float*)d_in[4];
    float* out = (float*)d_out;

    dim3 block(256);
    if (ws_size >= WS_NEED) {
        ushort* xt = (ushort*)d_ws;
        ushort* wt = xt + XT_ELEMS;
        wt_transform_kernel<<<dim3((int)(WT_ELEMS / 256)), block, 0, stream>>>(weight, wt);
        xt_transpose_kernel<<<dim3(NI * NTILE), block, 0, stream>>>(x, xt);
        dcn_mfma2_kernel<<<dim3(NI * NTILE), block, 0, stream>>>(
            xt, wt, offset, mask, bias, out);
    } else {
        dcn_fallback_kernel<<<dim3(NI * NTILE), block, 0, stream>>>(
            x, offset, mask, weight, bias, out);
    }
}